// Round 7
// baseline (158.209 us; speedup 1.0000x reference)
//
#include <hip/hip_runtime.h>

// B=64, IMG=1024, IND=64, E=4, FF=16. Inputs fp32, output fp32.
// Algebraic collapse (validated rounds 5/6, absmax 0.0): scalar token iv
// through affine stem -> softmax weight exp(alpha_r*iv_t) (row-const cancels),
// attention out = HB*rho + HC with rho = S1/S0.
// Round 7: single kernel. Classifier fused via block-reduce + device-scope
// atomicAdd into acc[B][3]; last block (ticket counter) does bias+softmax.
#define B_    64
#define IMG_  1024
#define IND_  64
#define NTHR  256
#define IMG_BPB 16
#define NBLK  (B_ * IMG_BPB + B_)   // 1088

enum {
  W_IN = 0, B_IN = 4, QKV_W = 8, QKV_B = 56, O_W = 68, O_B = 84,
  LN1G = 88, LN1B = 92, FF1W = 96, FF1B = 160, FF2W = 176, FF2B = 240,
  LN2G = 244, LN2B = 248, W_OUT = 252, B_OUT = 256, WTOT = 257
};

struct KArgs {
  const float* in[36];
  float* acc;          // [B_][3] f32, zeroed by memset node
  unsigned int* cnt;   // ticket counter, zeroed by memset node
  float* out;          // [B_][3] f32 (d_out)
};

__device__ __forceinline__ void stage(float* dst, const float* src, int n, int tid) {
  for (int i = tid; i < n; i += NTHR) dst[i] = src[i];
}

__global__ __launch_bounds__(NTHR) void fused_all(KArgs A) {
  const int blk = blockIdx.x;
  const int tid = threadIdx.x;
  const bool is_img = blk < B_ * IMG_BPB;

  __shared__ float w[WTOT];
  __shared__ float iv[IMG_];
  __shared__ float red[4][3];
  __shared__ unsigned int sticket;

  int batch, row, S, tb;
  const float* xin;
  if (is_img) {
    batch = blk >> 4; row = ((blk & 15) << 6) + (tid >> 2); S = IMG_;
    xin = A.in[0] + batch * IMG_; tb = 10;
  } else {
    batch = blk - B_ * IMG_BPB; row = tid >> 2; S = IND_;
    xin = A.in[1] + batch * IND_; tb = 22;
  }
  const int g = is_img ? row : (IMG_ + row);   // w_cls row index

  // ---- stage weights + token sequence into LDS ----
  stage(w + W_IN,  A.in[is_img ? 2 : 4], 4,  tid);
  stage(w + B_IN,  A.in[is_img ? 3 : 5], 4,  tid);
  stage(w + W_OUT, A.in[is_img ? 6 : 8], 4,  tid);
  stage(w + B_OUT, A.in[is_img ? 7 : 9], 1,  tid);
  stage(w + QKV_W, A.in[tb + 0], 48, tid);
  stage(w + QKV_B, A.in[tb + 1], 12, tid);
  stage(w + O_W,   A.in[tb + 2], 16, tid);
  stage(w + O_B,   A.in[tb + 3], 4,  tid);
  stage(w + LN1G,  A.in[tb + 4], 4,  tid);
  stage(w + LN1B,  A.in[tb + 5], 4,  tid);
  stage(w + FF1W,  A.in[tb + 6], 64, tid);
  stage(w + FF1B,  A.in[tb + 7], 16, tid);
  stage(w + FF2W,  A.in[tb + 8], 64, tid);
  stage(w + FF2B,  A.in[tb + 9], 4,  tid);
  stage(w + LN2G,  A.in[tb + 10], 4, tid);
  stage(w + LN2B,  A.in[tb + 11], 4, tid);
  for (int i = tid; i < S; i += NTHR) iv[i] = xin[i];
  __syncthreads();

  // ---- derived affine constants (uniform, redundant per thread) ----
  float qd[4], qb[4], kd[4], vd[4], vb[4];
#pragma unroll
  for (int j = 0; j < 4; j++) {
    float a0 = 0.f, a1 = 0.f, a2 = 0.f, b0 = 0.f, b2 = 0.f;
#pragma unroll
    for (int e = 0; e < 4; e++) {
      const float we = w[W_IN + e], be = w[B_IN + e];
      a0 += we * w[QKV_W + e * 12 + j];      b0 += be * w[QKV_W + e * 12 + j];
      a1 += we * w[QKV_W + e * 12 + 4 + j];
      a2 += we * w[QKV_W + e * 12 + 8 + j];  b2 += be * w[QKV_W + e * 12 + 8 + j];
    }
    qd[j] = a0; qb[j] = b0 + w[QKV_B + j];
    kd[j] = a1;
    vd[j] = a2; vb[j] = b2 + w[QKV_B + 8 + j];
  }
  float c1 = 0.f, c0 = 0.f;
#pragma unroll
  for (int j = 0; j < 4; j++) { c1 += qd[j] * kd[j]; c0 += qb[j] * kd[j]; }
  float HB[4], HC[4];
#pragma unroll
  for (int j = 0; j < 4; j++) {
    float s1 = 0.f, s2 = 0.f;
#pragma unroll
    for (int f = 0; f < 4; f++) {
      s1 += vd[f] * w[O_W + f * 4 + j];
      s2 += vb[f] * w[O_W + f * 4 + j];
    }
    HB[j] = s1; HC[j] = w[B_IN + j] + s2 + w[O_B + j];
  }

  const float ivr = iv[row];
  const float ah = 0.5f * 1.4426950408889634f * (c1 * ivr + c0);

  // ---- 4-lane split streaming softmax sums ----
  const int c = tid & 3;
  const int nch = S >> 2;
  float S0 = 0.f, S1 = 0.f;
  for (int ci = c; ci < nch; ci += 4) {
    const float4 t4 = *reinterpret_cast<const float4*>(&iv[ci << 2]);
    float p;
    p = exp2f(ah * t4.x); S0 += p; S1 = fmaf(p, t4.x, S1);
    p = exp2f(ah * t4.y); S0 += p; S1 = fmaf(p, t4.y, S1);
    p = exp2f(ah * t4.z); S0 += p; S1 = fmaf(p, t4.z, S1);
    p = exp2f(ah * t4.w); S0 += p; S1 = fmaf(p, t4.w, S1);
  }
  S0 += __shfl_xor(S0, 1); S1 += __shfl_xor(S1, 1);
  S0 += __shfl_xor(S0, 2); S1 += __shfl_xor(S1, 2);
  const float rho = S1 / S0;

  // ---- per-row tail (redundant on 4 lanes) ----
  float h[4];
#pragma unroll
  for (int j = 0; j < 4; j++) h[j] = w[W_IN + j] * ivr + HB[j] * rho + HC[j];
  {
    const float m = 0.25f * (h[0] + h[1] + h[2] + h[3]);
    float v = 0.f;
#pragma unroll
    for (int j = 0; j < 4; j++) { const float d = h[j] - m; v += d * d; }
    const float rs = rsqrtf(v * 0.25f + 1e-5f);
#pragma unroll
    for (int j = 0; j < 4; j++) h[j] = (h[j] - m) * rs * w[LN1G + j] + w[LN1B + j];
  }
  float f2[4] = {w[FF2B + 0], w[FF2B + 1], w[FF2B + 2], w[FF2B + 3]};
#pragma unroll
  for (int t = 0; t < 16; t++) {
    float u = w[FF1B + t];
#pragma unroll
    for (int j = 0; j < 4; j++) u += h[j] * w[FF1W + j * 16 + t];
    u = fmaxf(u, 0.f);
#pragma unroll
    for (int j = 0; j < 4; j++) f2[j] += u * w[FF2W + t * 4 + j];
  }
  float h2[4];
#pragma unroll
  for (int j = 0; j < 4; j++) h2[j] = h[j] + f2[j];
  {
    const float m = 0.25f * (h2[0] + h2[1] + h2[2] + h2[3]);
    float v = 0.f;
#pragma unroll
    for (int j = 0; j < 4; j++) { const float d = h2[j] - m; v += d * d; }
    const float rs = rsqrtf(v * 0.25f + 1e-5f);
#pragma unroll
    for (int j = 0; j < 4; j++) h2[j] = (h2[j] - m) * rs * w[LN2G + j] + w[LN2B + j];
  }
  float out = w[B_OUT];
#pragma unroll
  for (int j = 0; j < 4; j++) out += h2[j] * w[W_OUT + j];

  // ---- fused classifier partial: rows x w_cls, block-reduce, 3 atomics ----
  float p0 = 0.f, p1 = 0.f, p2 = 0.f;
  if (c == 0) {
    const float* wc = A.in[34] + 3 * g;
    p0 = out * wc[0]; p1 = out * wc[1]; p2 = out * wc[2];
  }
#pragma unroll
  for (int m = 1; m < 64; m <<= 1) {
    p0 += __shfl_xor(p0, m); p1 += __shfl_xor(p1, m); p2 += __shfl_xor(p2, m);
  }
  if ((tid & 63) == 0) {
    const int wv = tid >> 6;
    red[wv][0] = p0; red[wv][1] = p1; red[wv][2] = p2;
  }
  __syncthreads();
  if (tid == 0) {
    atomicAdd(&A.acc[batch * 3 + 0], red[0][0] + red[1][0] + red[2][0] + red[3][0]);
    atomicAdd(&A.acc[batch * 3 + 1], red[0][1] + red[1][1] + red[2][1] + red[3][1]);
    atomicAdd(&A.acc[batch * 3 + 2], red[0][2] + red[1][2] + red[2][2] + red[3][2]);
    __threadfence();
    sticket = atomicAdd(A.cnt, 1u);
  }
  __syncthreads();

  // ---- last block: bias + softmax + store ----
  if (sticket == NBLK - 1) {
    __threadfence();
    if (tid < B_) {
      const float z0 = atomicAdd(&A.acc[tid * 3 + 0], 0.0f) + A.in[35][0];
      const float z1 = atomicAdd(&A.acc[tid * 3 + 1], 0.0f) + A.in[35][1];
      const float z2 = atomicAdd(&A.acc[tid * 3 + 2], 0.0f) + A.in[35][2];
      const float mx = fmaxf(z0, fmaxf(z1, z2));
      const float e0 = __expf(z0 - mx), e1 = __expf(z1 - mx), e2 = __expf(z2 - mx);
      const float rs = 1.f / (e0 + e1 + e2);
      A.out[tid * 3 + 0] = e0 * rs;
      A.out[tid * 3 + 1] = e1 * rs;
      A.out[tid * 3 + 2] = e2 * rs;
    }
  }
}

extern "C" void kernel_launch(void* const* d_in, const int* in_sizes, int n_in,
                              void* d_out, int out_size, void* d_ws, size_t ws_size,
                              hipStream_t stream) {
  KArgs A;
  for (int i = 0; i < 36; i++) A.in[i] = (const float*)d_in[i];
  A.acc = (float*)d_ws;                       // 192 floats
  A.cnt = (unsigned int*)((float*)d_ws + 192);
  A.out = (float*)d_out;

  hipMemsetAsync(d_ws, 0, 1024, stream);      // zero acc + ticket (graph-legal)
  fused_all<<<NBLK, NTHR, 0, stream>>>(A);
}